// Round 4
// baseline (26.366 us; speedup 1.0000x reference)
//
#include <hip/hip_runtime.h>
#include <hip/hip_bf16.h>

#define B_SZ   256
#define N_IN   128
#define F_IN   64
#define G_SZ   128
#define F_OUT  64
#define S_SZ   16
#define K_TOT  1024   // S_SZ * F_IN

#define M_TILE 128
#define BK     64
#define NSTEP  16     // K_TOT / BK
#define THREADS 512   // 8 waves: wave grid 4 (M) x 2 (N)

#define WSTRIDE 72    // W LDS pad: 144 B rows

typedef __attribute__((ext_vector_type(8))) short short8;  // 8 bf16
typedef __attribute__((ext_vector_type(4))) float f32x4;
typedef unsigned short u16;
typedef unsigned int   u32;

static __device__ __forceinline__ u32 packbf2(float a, float b) {
    // low 16 = a, high 16 = b (RNE); compiler emits v_cvt_pk_bf16_f32
    __hip_bfloat162 h = __float22bfloat162_rn(make_float2(a, b));
    union { __hip_bfloat162 h; u32 u; } c; c.h = h;
    return c.u;
}

// ---------------- pass 1: x fp32 -> bf16 (same [B][N][F] layout) ----------------
__global__ __launch_bounds__(256)
void convert_x_kernel(const float* __restrict__ x, u16* __restrict__ xbf) {
    const int i = blockIdx.x * 256 + threadIdx.x;    // 8 floats per thread, exact
    const float4 v0 = reinterpret_cast<const float4*>(x)[i * 2];
    const float4 v1 = reinterpret_cast<const float4*>(x)[i * 2 + 1];
    uint4 p;
    p.x = packbf2(v0.x, v0.y); p.y = packbf2(v0.z, v0.w);
    p.z = packbf2(v1.x, v1.y); p.w = packbf2(v1.z, v1.w);
    reinterpret_cast<uint4*>(xbf)[i] = p;
}

// ---------------- pass 2: grouped GEMM ----------------
// A tile: [128 m][64 k] bf16, LINEAR LDS (no pad), content XOR-swizzled:
//   physical 16B-slot p of row m holds global bytes p*16 ^ ((m&7)<<4).
// Staged via global_load_lds (dest linear, source pre-swizzled) when ABF,
// else reg-staged fp32->bf16 with the same swizzle applied on ds_write.
template<bool ABF>
__global__ __launch_bounds__(THREADS)
void sparse_linear_kernel(const float* __restrict__ x,
                          const u16*   __restrict__ xbf,
                          const int*   __restrict__ idx,
                          const float* __restrict__ W,
                          const float* __restrict__ bias,
                          float*       __restrict__ out)
{
    __shared__ u16 Alds[2][M_TILE * 64];      // 16 KB each, linear
    __shared__ u16 Wlds[2][F_OUT * WSTRIDE];  // padded

    const int blk   = blockIdx.x;
    const int g     = blk & 127;              // blk and blk+128 share W[g]; same XCD (128%8==0)
    const int mt    = blk >> 7;
    const int bbase = mt * M_TILE;

    const int tid  = threadIdx.x;
    const int wave = tid >> 6;
    const int lane = tid & 63;
    const int wr   = wave >> 1;               // 0..3 (M, 32 rows)
    const int wc   = wave & 1;                // 0..1 (N, 32 cols)
    const int lmod = lane & 15;
    const int ldiv = lane >> 4;

    // ---- A staging coords: 2 chunks, id = tid + i*512 in 0..1023 ----
    int amA[2], asubA[2];
    #pragma unroll
    for (int i = 0; i < 2; ++i) {
        int id = tid + i * THREADS;
        amA[i]   = id >> 3;                   // m row 0..127
        asubA[i] = id & 7;                    // 16B slot 0..7
    }

    // ---- W staging coords: 2 chunks ----
    const float* wptr[2]; int lofsW[2];
    #pragma unroll
    for (int i = 0; i < 2; ++i) {
        int id = tid + i * THREADS;
        int o  = id >> 4;                     // 0..63
        int fo = (id & 15) << 2;              // float col
        wptr[i]  = W + (size_t)g * (F_OUT * K_TOT) + (size_t)o * K_TOT + fo;
        lofsW[i] = o * (WSTRIDE * 2) + fo * 2;
    }

    int rows[NSTEP];
    #pragma unroll
    for (int s = 0; s < NSTEP; ++s) rows[s] = idx[g * S_SZ + s];

    f32x4  acc[2][2] = {};
    float4 rw[2][2];                          // W depth-2 prefetch sets

    // A stage for K-step t into LDS buffer buf
    #define LOADA(t, buf)                                                       \
        {                                                                       \
            if constexpr (ABF) {                                                \
                _Pragma("unroll")                                               \
                for (int i = 0; i < 2; ++i) {                                   \
                    const char* gp = (const char*)xbf +                         \
                        (((size_t)(bbase + amA[i]) << 14) +                     \
                         ((size_t)rows[t] << 7) +                               \
                         ((asubA[i] * 16) ^ ((amA[i] & 7) << 4)));              \
                    __builtin_amdgcn_global_load_lds(                           \
                        (const __attribute__((address_space(1))) void*)gp,      \
                        (__attribute__((address_space(3))) void*)                \
                            (&Alds[buf][(tid + i * THREADS) * 8]),              \
                        16, 0, 0);                                              \
                }                                                               \
            } else {                                                            \
                _Pragma("unroll")                                               \
                for (int i = 0; i < 2; ++i) {                                   \
                    int f0 = (asubA[i] * 8) ^ ((amA[i] & 7) << 3);              \
                    const float* gp = x + ((size_t)(bbase + amA[i]) << 13)      \
                                        + (rows[t] << 6) + f0;                  \
                    float4 v0 = *reinterpret_cast<const float4*>(gp);           \
                    float4 v1 = *reinterpret_cast<const float4*>(gp + 4);       \
                    uint4 q;                                                    \
                    q.x = packbf2(v0.x, v0.y); q.y = packbf2(v0.z, v0.w);       \
                    q.z = packbf2(v1.x, v1.y); q.w = packbf2(v1.z, v1.w);       \
                    *reinterpret_cast<uint4*>((char*)&Alds[buf][0] +            \
                        (tid + i * THREADS) * 16) = q;                          \
                }                                                               \
            }                                                                   \
        }

    #define LOADW(t, s)                                                         \
        {                                                                       \
            _Pragma("unroll")                                                   \
            for (int i = 0; i < 2; ++i)                                         \
                rw[s][i] = *reinterpret_cast<const float4*>(wptr[i] + (t) * BK);\
        }

    #define STOREW(s, buf)                                                      \
        {                                                                       \
            _Pragma("unroll")                                                   \
            for (int i = 0; i < 2; ++i) {                                       \
                uint2 p;                                                        \
                p.x = packbf2(rw[s][i].x, rw[s][i].y);                          \
                p.y = packbf2(rw[s][i].z, rw[s][i].w);                          \
                *reinterpret_cast<uint2*>(                                      \
                    reinterpret_cast<char*>(Wlds[buf]) + lofsW[i]) = p;         \
            }                                                                   \
        }

    #define COMPUTE(buf)                                                        \
        {                                                                       \
            _Pragma("unroll")                                                   \
            for (int ks = 0; ks < 2; ++ks) {                                    \
                const int kb2 = ks * 64 + ldiv * 16;   /* frag byte col */      \
                short8 a[2], bfr[2];                                            \
                _Pragma("unroll")                                               \
                for (int mi = 0; mi < 2; ++mi) {                                \
                    const int r = wr * 32 + mi * 16 + lmod;                     \
                    a[mi] = *reinterpret_cast<const short8*>(                   \
                        reinterpret_cast<const char*>(Alds[buf]) +              \
                        r * 128 + (kb2 ^ ((r & 7) << 4)));                      \
                }                                                               \
                _Pragma("unroll")                                               \
                for (int ni = 0; ni < 2; ++ni)                                  \
                    bfr[ni] = *reinterpret_cast<const short8*>(                 \
                        reinterpret_cast<const char*>(Wlds[buf]) +              \
                        (wc * 32 + ni * 16 + lmod) * (WSTRIDE * 2) + kb2);      \
                _Pragma("unroll")                                               \
                for (int mi = 0; mi < 2; ++mi)                                  \
                    _Pragma("unroll")                                           \
                    for (int ni = 0; ni < 2; ++ni)                              \
                        acc[mi][ni] = __builtin_amdgcn_mfma_f32_16x16x32_bf16(  \
                            a[mi], bfr[ni], acc[mi][ni], 0, 0, 0);              \
            }                                                                   \
        }

    // ---- prologue ----
    LOADA(0, 0);
    LOADW(0, 0);
    LOADW(1, 1);
    STOREW(0, 0);

    // ---- main loop: A depth-1 via global_load_lds, W depth-2 via regs ----
    #pragma unroll
    for (int t = 0; t < NSTEP; ++t) {
        __syncthreads();                                  // buf t&1 ready
        if (t + 1 < NSTEP) LOADA(t + 1, (t + 1) & 1);
        if (t + 2 < NSTEP) LOADW(t + 2, t & 1);
        COMPUTE(t & 1);
        if (t + 1 < NSTEP) STOREW((t + 1) & 1, (t + 1) & 1);
    }

    // ---- epilogue ----
    const int rowbase = bbase + wr * 32 + (ldiv << 2);
    #pragma unroll
    for (int ni = 0; ni < 2; ++ni) {
        const int o  = wc * 32 + ni * 16 + lmod;
        const float bv = bias[g * F_OUT + o];
        #pragma unroll
        for (int mi = 0; mi < 2; ++mi) {
            #pragma unroll
            for (int r = 0; r < 4; ++r) {
                const int brow = rowbase + mi * 16 + r;
                out[(size_t)brow * (G_SZ * F_OUT) + g * F_OUT + o] = acc[mi][ni][r] + bv;
            }
        }
    }
}

extern "C" void kernel_launch(void* const* d_in, const int* in_sizes, int n_in,
                              void* d_out, int out_size, void* d_ws, size_t ws_size,
                              hipStream_t stream) {
    const float* x    = (const float*)d_in[0];
    const int*   idx  = (const int*)d_in[1];
    const float* W    = (const float*)d_in[2];
    const float* bias = (const float*)d_in[3];
    float*       out  = (float*)d_out;

    const size_t need = (size_t)B_SZ * N_IN * F_IN * sizeof(u16);   // 4 MB
    if (ws_size >= need) {
        u16* xbf = (u16*)d_ws;
        convert_x_kernel<<<dim3((B_SZ * N_IN * F_IN) / 8 / 256), dim3(256), 0, stream>>>(x, xbf);
        sparse_linear_kernel<true><<<dim3(G_SZ * (B_SZ / M_TILE)), dim3(THREADS), 0, stream>>>(
            x, xbf, idx, W, bias, out);
    } else {
        sparse_linear_kernel<false><<<dim3(G_SZ * (B_SZ / M_TILE)), dim3(THREADS), 0, stream>>>(
            x, nullptr, idx, W, bias, out);
    }
}